// Round 8
// baseline (216.710 us; speedup 1.0000x reference)
//
#include <hip/hip_runtime.h>

// Shape fixed by reference: (2,1,160,160,160) fp32, window 11, zero-pad box filter.
// Fields reduced via u=x+y, v=x-y: box{u, v, u^2, v^2} packed in one float4.
// R7 = R4 structure (best measured: stage-with-prefetch | W | H | redist+ring)
//      + last-block-done final reduction (no 2nd kernel) + CD=16 for residency.
#define DIMX 160
#define DIMY 160
#define DIMZ 160
#define BC   2
#define NTOT (BC * DIMZ * DIMY * DIMX)   // 8,192,000
#define PAD  5
#define TS   16                  // tile size in H and W
#define HS   26                  // TS + 2*PAD rows
#define XS4  10                  // stage row stride in float4 (8 used + 2 pad)
#define WPS  17                  // wp row stride in float4 (breaks bank aliasing)
#define CD   16                  // D-chunk per block (16: +25% blocks vs 20, +8% work)
#define NCH  (DIMZ / CD)         // 10
#define NTH  (DIMY / TS)         // 10
#define NTW  (DIMX / TS)         // 10
#define NBLK (NCH * BC * NTH * NTW)  // 2000 blocks

static_assert(NTOT == 8192000, "size mismatch");

__device__ __forceinline__ float4 f4add(float4 a, float4 b) {
  return make_float4(a.x + b.x, a.y + b.y, a.z + b.z, a.w + b.w);
}
__device__ __forceinline__ float4 f4sub(float4 a, float4 b) {
  return make_float4(a.x - b.x, a.y - b.y, a.z - b.z, a.w - b.w);
}

// Ring slot update with compile-time index K (keeps ring[] in VGPRs).
#define RING_CASE(K) case K: {                 \
    sums = f4add(sums, f4sub(Sv, ring[K]));    \
    ring[K] = Sv;                              \
  } break;

__device__ __forceinline__ float ssim_term(float4 sm, float inv, float c1, float c2) {
  const float mu_u = sm.x * inv, mu_v = sm.y * inv;
  const float Euu  = sm.z * inv, Evv  = sm.w * inv;
  const float P = mu_u * mu_u, Q = mu_v * mu_v;
  const float sgu = Euu - P, sgv = Evv - Q;
  const float num = (0.5f * (P - Q) + c1) * (0.5f * (sgu - sgv) + c2);
  const float den = (0.5f * (P + Q) + c1) * (0.5f * (sgu + sgv) + c2);
  const float ssim = num * __builtin_amdgcn_rcpf(den + 1e-8f);
  const float val  = 0.5f * (1.f - ssim);
  return fminf(fmaxf(val, 0.f), 1.f);
}

__global__ __launch_bounds__(256) void fused_ssim(const float* __restrict__ X,
                                                  const float* __restrict__ Y,
                                                  float* __restrict__ pssim,
                                                  float* __restrict__ pl1,
                                                  unsigned int* __restrict__ ticket,
                                                  float* __restrict__ out) {
  __shared__ float4 us4[HS * XS4];   // staged u slab (26 rows x 8 used float4)
  __shared__ float4 vs4[HS * XS4];   // staged v slab
  __shared__ float4 wpf[HS * WPS];   // W-passed {su,sv,suu,svv}, stride 17
  __shared__ float4 Sb[TS * TS];     // H-passed per-voxel field vector

  const int tid = threadIdx.x;
  const int bx  = blockIdx.x;
  const int tw  = bx % NTW;
  const int th  = (bx / NTW) % NTH;
  const int b   = (bx / (NTW * NTH)) % BC;
  const int ch  =  bx / (NTW * NTH * BC);
  const int h0 = th * TS, w0 = tw * TS, c0 = ch * CD;
  const size_t bbase = (size_t)b * (DIMZ * DIMY * DIMX);

  // staging decomposition: 208 threads = 26 rows x 8 float4-cols (w0-8 .. w0+23)
  const int sr  = tid >> 3, sc4 = tid & 7;
  const int sgh = h0 - PAD + sr;
  const int sgw = w0 - 8 + (sc4 << 2);
  const bool sok = (tid < 208) && ((unsigned)sgh < (unsigned)DIMY) &&
                   ((unsigned)sgw < (unsigned)DIMX);
  const bool l1own = (sr >= PAD) && (sr < PAD + TS) && (sc4 >= 2) && (sc4 < 6);
  const size_t sgoff = bbase + (size_t)sgh * DIMX + sgw;   // only used when sok

  float4 ring[11];
#pragma unroll
  for (int k = 0; k < 11; ++k) ring[k] = make_float4(0.f, 0.f, 0.f, 0.f);
  float4 sums = make_float4(0.f, 0.f, 0.f, 0.f);
  float l1loc = 0.f, ssloc = 0.f;

  const float inv = 1.0f / 1331.0f;             // 1/11^3
  const float c1  = 0.01f / (4096.f * 4096.f);  // K1 / data_range^2 (faithful to ref)
  const float c2  = 0.03f / (4096.f * 4096.f);

  // prefetch first slab (d = c0-PAD) into regs
  float4 xq = make_float4(0.f, 0.f, 0.f, 0.f), yq = xq;
  if (sok && (unsigned)(c0 - PAD) < (unsigned)DIMZ) {
    const size_t g = sgoff + (size_t)(c0 - PAD) * (DIMY * DIMX);
    xq = *(const float4*)(X + g);
    yq = *(const float4*)(Y + g);
  }

  int ph = (c0 - PAD + 22) % 11;   // uniform ring phase

  for (int d = c0 - PAD; d < c0 + CD + PAD; ++d) {
    const bool dval = (unsigned)d < (unsigned)DIMZ;
    const bool dIn  = (d >= c0) && (d < c0 + CD);

    // --- stage u,v from prefetched regs; fuse smooth-L1; issue next prefetch ---
    if (tid < 208) {
      if (dval) {
        const float4 u = f4add(xq, yq);
        const float4 v = f4sub(xq, yq);
        us4[sr * XS4 + sc4] = u;
        vs4[sr * XS4 + sc4] = v;
        if (dIn && l1own) {
          const float a0 = fabsf(v.x), a1 = fabsf(v.y);
          const float a2 = fabsf(v.z), a3 = fabsf(v.w);
          l1loc += (a0 < 1.f) ? 0.5f * a0 * a0 : a0 - 0.5f;
          l1loc += (a1 < 1.f) ? 0.5f * a1 * a1 : a1 - 0.5f;
          l1loc += (a2 < 1.f) ? 0.5f * a2 * a2 : a2 - 0.5f;
          l1loc += (a3 < 1.f) ? 0.5f * a3 * a3 : a3 - 0.5f;
        }
      }
      const int dn = d + 1;
      if (sok && (unsigned)dn < (unsigned)DIMZ) {
        const size_t g = sgoff + (size_t)dn * (DIMY * DIMX);
        xq = *(const float4*)(X + g);   // in flight across the barriers below
        yq = *(const float4*)(Y + g);
      } else {
        xq = make_float4(0.f, 0.f, 0.f, 0.f);
        yq = make_float4(0.f, 0.f, 0.f, 0.f);
      }
    }
    __syncthreads();

    // --- W-pass: 104 threads x 4 sliding outputs; 5 b128 reads per field ---
    if (dval && tid < 104) {
      const int wr = tid >> 2, wg = tid & 3;
      const int rb = wr * XS4 + wg;
      const int o  = wr * WPS + (wg << 2);
      float su[4], sv[4], suu[4], svv[4];
      float t[20];
      {  // field u
        float4 q;
        q = us4[rb    ]; t[0]=q.x;  t[1]=q.y;  t[2]=q.z;  t[3]=q.w;
        q = us4[rb + 1]; t[4]=q.x;  t[5]=q.y;  t[6]=q.z;  t[7]=q.w;
        q = us4[rb + 2]; t[8]=q.x;  t[9]=q.y;  t[10]=q.z; t[11]=q.w;
        q = us4[rb + 3]; t[12]=q.x; t[13]=q.y; t[14]=q.z; t[15]=q.w;
        q = us4[rb + 4]; t[16]=q.x; t[17]=q.y; t[18]=q.z; t[19]=q.w;
        float s = 0.f, ss = 0.f;
#pragma unroll
        for (int j = 3; j <= 13; ++j) { s += t[j]; ss = fmaf(t[j], t[j], ss); }
        su[0] = s; suu[0] = ss;
#pragma unroll
        for (int k = 1; k < 4; ++k) {
          const float nw = t[13 + k], od = t[2 + k];
          s += nw - od;
          ss = fmaf(nw, nw, fmaf(-od, od, ss));
          su[k] = s; suu[k] = ss;
        }
      }
      {  // field v
        float4 q;
        q = vs4[rb    ]; t[0]=q.x;  t[1]=q.y;  t[2]=q.z;  t[3]=q.w;
        q = vs4[rb + 1]; t[4]=q.x;  t[5]=q.y;  t[6]=q.z;  t[7]=q.w;
        q = vs4[rb + 2]; t[8]=q.x;  t[9]=q.y;  t[10]=q.z; t[11]=q.w;
        q = vs4[rb + 3]; t[12]=q.x; t[13]=q.y; t[14]=q.z; t[15]=q.w;
        q = vs4[rb + 4]; t[16]=q.x; t[17]=q.y; t[18]=q.z; t[19]=q.w;
        float s = 0.f, ss = 0.f;
#pragma unroll
        for (int j = 3; j <= 13; ++j) { s += t[j]; ss = fmaf(t[j], t[j], ss); }
        sv[0] = s; svv[0] = ss;
#pragma unroll
        for (int k = 1; k < 4; ++k) {
          const float nw = t[13 + k], od = t[2 + k];
          s += nw - od;
          ss = fmaf(nw, nw, fmaf(-od, od, ss));
          sv[k] = s; svv[k] = ss;
        }
      }
#pragma unroll
      for (int k = 0; k < 4; ++k)
        wpf[o + k] = make_float4(su[k], sv[k], suu[k], svv[k]);
    }
    __syncthreads();

    // --- H-pass: 64 threads x 4 sliding outputs (14 b128 reads, 4 writes) ---
    if (dval && tid < 64) {
      const int qt = tid >> 4, hw = tid & 15;
      const int base = (qt << 2) * WPS + hw;
      const float4 T0 = wpf[base];
      const float4 T1 = wpf[base + WPS];
      const float4 T2 = wpf[base + 2 * WPS];
      float4 S = f4add(f4add(T0, T1), T2);
#pragma unroll
      for (int j = 3; j <= 10; ++j) S = f4add(S, wpf[base + j * WPS]);
      Sb[((qt << 2) + 0) * TS + hw] = S;
      S = f4sub(f4add(S, wpf[base + 11 * WPS]), T0);
      Sb[((qt << 2) + 1) * TS + hw] = S;
      S = f4sub(f4add(S, wpf[base + 12 * WPS]), T1);
      Sb[((qt << 2) + 2) * TS + hw] = S;
      S = f4sub(f4add(S, wpf[base + 13 * WPS]), T2);
      Sb[((qt << 2) + 3) * TS + hw] = S;
    }
    __syncthreads();

    // --- redistribute + D-ring update + SSIM ---
    float4 Sv = make_float4(0.f, 0.f, 0.f, 0.f);
    if (dval) Sv = Sb[tid];
    switch (ph) {
      RING_CASE(0) RING_CASE(1) RING_CASE(2) RING_CASE(3) RING_CASE(4)
      RING_CASE(5) RING_CASE(6) RING_CASE(7) RING_CASE(8) RING_CASE(9)
      RING_CASE(10)
    }
    ph = (ph == 10) ? 0 : ph + 1;
    if (d >= c0 + PAD) ssloc += ssim_term(sums, inv, c1, c2);
  }

  // --- block reduction -> per-block partials ---
#pragma unroll
  for (int off = 32; off > 0; off >>= 1) {
    ssloc += __shfl_down(ssloc, off, 64);
    l1loc += __shfl_down(l1loc, off, 64);
  }
  __syncthreads();                 // LDS compute use done; reuse Sb as scratch
  float* scr = (float*)Sb;
  const int lane = tid & 63, wv = tid >> 6;
  if (lane == 0) {
    scr[wv * 2]     = ssloc;
    scr[wv * 2 + 1] = l1loc;
  }
  __syncthreads();
  if (tid == 0) {
    pssim[bx] = scr[0] + scr[2] + scr[4] + scr[6];
    pl1[bx]   = scr[1] + scr[3] + scr[5] + scr[7];
    __threadfence();                               // release partials (device scope)
    const unsigned old = atomicAdd(ticket, 1u);    // device-scope by default
    scr[8] = (old == NBLK - 1) ? 1.f : 0.f;        // broadcast last-block flag
  }
  __syncthreads();

  // --- last block: reduce all partials and emit the scalar loss ---
  if (scr[8] != 0.f) {
    __threadfence();   // acquire: make all blocks' partial writes visible
    double s = 0.0, l = 0.0;
    for (int i = tid; i < NBLK; i += 256) {
      s += (double)pssim[i];
      l += (double)pl1[i];
    }
#pragma unroll
    for (int off = 32; off > 0; off >>= 1) {
      s += __shfl_down(s, off, 64);
      l += __shfl_down(l, off, 64);
    }
    double* dsm = (double*)Sb;   // reuse LDS as 8 doubles (after a sync)
    __syncthreads();
    if (lane == 0) { dsm[wv * 2] = s; dsm[wv * 2 + 1] = l; }
    __syncthreads();
    if (tid == 0) {
      const double ssm = (dsm[0] + dsm[2] + dsm[4] + dsm[6]) / (double)NTOT;
      const double l1m = (dsm[1] + dsm[3] + dsm[5] + dsm[7]) / (double)NTOT;
      out[0] = (float)(0.85 * ssm + 0.15 * l1m);
    }
  }
}

extern "C" void kernel_launch(void* const* d_in, const int* in_sizes, int n_in,
                              void* d_out, int out_size, void* d_ws, size_t ws_size,
                              hipStream_t stream) {
  const float* X = (const float*)d_in[0];
  const float* Y = (const float*)d_in[1];
  float* out = (float*)d_out;

  float* pssim = (float*)d_ws;              // NBLK floats
  float* pl1   = pssim + NBLK;              // NBLK floats
  unsigned int* ticket = (unsigned int*)(pl1 + NBLK);

  hipMemsetAsync(ticket, 0, sizeof(unsigned int), stream);
  fused_ssim<<<NBLK, 256, 0, stream>>>(X, Y, pssim, pl1, ticket, out);
}

// Round 9
// 170.718 us; speedup vs baseline: 1.2694x; 1.2694x over previous
//
#include <hip/hip_runtime.h>

// Shape fixed by reference: (2,1,160,160,160) fp32, window 11, zero-pad box filter.
// Fields reduced via u=x+y, v=x-y: box{u, v, u^2, v^2} packed in one float4.
// R8 = exact R4 structure (best measured: stage-with-prefetch | W | H | redist,
//      CD=20, two kernels) + XCD-aware blockIdx swizzle: bx = tile*16 + (ch,b)
//      pair, so under round-robin XCD dispatch (bx%8) all tiles of one plane-set
//      share an XCD and halo re-reads hit its 4 MB L2.
#define DIMX 160
#define DIMY 160
#define DIMZ 160
#define BC   2
#define NTOT (BC * DIMZ * DIMY * DIMX)   // 8,192,000
#define PAD  5
#define TS   16                  // tile size in H and W
#define HS   26                  // TS + 2*PAD rows
#define XS4  10                  // stage row stride in float4 (8 used + 2 pad)
#define WPS  17                  // wp row stride in float4 (breaks bank aliasing)
#define CD   20                  // D-chunk per block
#define NCH  (DIMZ / CD)         // 8
#define NTH  (DIMY / TS)         // 10
#define NTW  (DIMX / TS)         // 10
#define NBLK (NCH * BC * NTH * NTW)  // 1600 blocks = 100 tiles x 16 (ch,b) pairs

static_assert(NTOT == 8192000, "size mismatch");

__device__ __forceinline__ float4 f4add(float4 a, float4 b) {
  return make_float4(a.x + b.x, a.y + b.y, a.z + b.z, a.w + b.w);
}
__device__ __forceinline__ float4 f4sub(float4 a, float4 b) {
  return make_float4(a.x - b.x, a.y - b.y, a.z - b.z, a.w - b.w);
}

// Ring slot update with compile-time index K (keeps ring[] in VGPRs).
#define RING_CASE(K) case K: {                 \
    sums = f4add(sums, f4sub(Sv, ring[K]));    \
    ring[K] = Sv;                              \
  } break;

__device__ __forceinline__ float ssim_term(float4 sm, float inv, float c1, float c2) {
  const float mu_u = sm.x * inv, mu_v = sm.y * inv;
  const float Euu  = sm.z * inv, Evv  = sm.w * inv;
  const float P = mu_u * mu_u, Q = mu_v * mu_v;
  const float sgu = Euu - P, sgv = Evv - Q;
  const float num = (0.5f * (P - Q) + c1) * (0.5f * (sgu - sgv) + c2);
  const float den = (0.5f * (P + Q) + c1) * (0.5f * (sgu + sgv) + c2);
  const float ssim = num * __builtin_amdgcn_rcpf(den + 1e-8f);
  const float val  = 0.5f * (1.f - ssim);
  return fminf(fmaxf(val, 0.f), 1.f);
}

__global__ __launch_bounds__(256) void fused_ssim(const float* __restrict__ X,
                                                  const float* __restrict__ Y,
                                                  float* __restrict__ pssim,
                                                  float* __restrict__ pl1) {
  __shared__ float4 us4[HS * XS4];   // staged u slab (26 rows x 8 used float4)
  __shared__ float4 vs4[HS * XS4];   // staged v slab
  __shared__ float4 wpf[HS * WPS];   // W-passed {su,sv,suu,svv}, stride 17
  __shared__ float4 Sb[TS * TS];     // H-passed per-voxel field vector

  const int tid = threadIdx.x;
  const int bx  = blockIdx.x;
  // XCD swizzle: p constant mod 8 over all 100 tiles of a (ch,b) plane-set.
  const int p  = bx & 15;            // (ch,b) pair index 0..15
  const int t  = bx >> 4;            // tile index 0..99
  const int ch = p >> 1;
  const int b  = p & 1;
  const int th = t / NTW;
  const int tw = t - th * NTW;
  const int h0 = th * TS, w0 = tw * TS, c0 = ch * CD;
  const size_t bbase = (size_t)b * (DIMZ * DIMY * DIMX);

  // staging decomposition: 208 threads = 26 rows x 8 float4-cols (w0-8 .. w0+23)
  const int sr  = tid >> 3, sc4 = tid & 7;
  const int sgh = h0 - PAD + sr;
  const int sgw = w0 - 8 + (sc4 << 2);
  const bool sok = (tid < 208) && ((unsigned)sgh < (unsigned)DIMY) &&
                   ((unsigned)sgw < (unsigned)DIMX);
  const bool l1own = (sr >= PAD) && (sr < PAD + TS) && (sc4 >= 2) && (sc4 < 6);
  const size_t sgoff = bbase + (size_t)sgh * DIMX + sgw;   // only used when sok

  float4 ring[11];
#pragma unroll
  for (int k = 0; k < 11; ++k) ring[k] = make_float4(0.f, 0.f, 0.f, 0.f);
  float4 sums = make_float4(0.f, 0.f, 0.f, 0.f);
  float l1loc = 0.f, ssloc = 0.f;

  const float inv = 1.0f / 1331.0f;             // 1/11^3
  const float c1  = 0.01f / (4096.f * 4096.f);  // K1 / data_range^2 (faithful to ref)
  const float c2  = 0.03f / (4096.f * 4096.f);

  // prefetch first slab (d = c0-PAD) into regs
  float4 xq = make_float4(0.f, 0.f, 0.f, 0.f), yq = xq;
  if (sok && (unsigned)(c0 - PAD) < (unsigned)DIMZ) {
    const size_t g = sgoff + (size_t)(c0 - PAD) * (DIMY * DIMX);
    xq = *(const float4*)(X + g);
    yq = *(const float4*)(Y + g);
  }

  int ph = (c0 - PAD + 22) % 11;   // uniform ring phase

  for (int d = c0 - PAD; d < c0 + CD + PAD; ++d) {
    const bool dval = (unsigned)d < (unsigned)DIMZ;
    const bool dIn  = (d >= c0) && (d < c0 + CD);

    // --- stage u,v from prefetched regs; fuse smooth-L1; issue next prefetch ---
    if (tid < 208) {
      if (dval) {
        const float4 u = f4add(xq, yq);
        const float4 v = f4sub(xq, yq);
        us4[sr * XS4 + sc4] = u;
        vs4[sr * XS4 + sc4] = v;
        if (dIn && l1own) {
          const float a0 = fabsf(v.x), a1 = fabsf(v.y);
          const float a2 = fabsf(v.z), a3 = fabsf(v.w);
          l1loc += (a0 < 1.f) ? 0.5f * a0 * a0 : a0 - 0.5f;
          l1loc += (a1 < 1.f) ? 0.5f * a1 * a1 : a1 - 0.5f;
          l1loc += (a2 < 1.f) ? 0.5f * a2 * a2 : a2 - 0.5f;
          l1loc += (a3 < 1.f) ? 0.5f * a3 * a3 : a3 - 0.5f;
        }
      }
      const int dn = d + 1;
      if (sok && (unsigned)dn < (unsigned)DIMZ) {
        const size_t g = sgoff + (size_t)dn * (DIMY * DIMX);
        xq = *(const float4*)(X + g);   // in flight across the barriers below
        yq = *(const float4*)(Y + g);
      } else {
        xq = make_float4(0.f, 0.f, 0.f, 0.f);
        yq = make_float4(0.f, 0.f, 0.f, 0.f);
      }
    }
    __syncthreads();

    // --- W-pass: 104 threads x 4 sliding outputs; 5 b128 reads per field ---
    if (dval && tid < 104) {
      const int wr = tid >> 2, wg = tid & 3;
      const int rb = wr * XS4 + wg;
      const int o  = wr * WPS + (wg << 2);
      float su[4], sv[4], suu[4], svv[4];
      float t4[20];
      {  // field u
        float4 q;
        q = us4[rb    ]; t4[0]=q.x;  t4[1]=q.y;  t4[2]=q.z;  t4[3]=q.w;
        q = us4[rb + 1]; t4[4]=q.x;  t4[5]=q.y;  t4[6]=q.z;  t4[7]=q.w;
        q = us4[rb + 2]; t4[8]=q.x;  t4[9]=q.y;  t4[10]=q.z; t4[11]=q.w;
        q = us4[rb + 3]; t4[12]=q.x; t4[13]=q.y; t4[14]=q.z; t4[15]=q.w;
        q = us4[rb + 4]; t4[16]=q.x; t4[17]=q.y; t4[18]=q.z; t4[19]=q.w;
        float s = 0.f, ss = 0.f;
#pragma unroll
        for (int j = 3; j <= 13; ++j) { s += t4[j]; ss = fmaf(t4[j], t4[j], ss); }
        su[0] = s; suu[0] = ss;
#pragma unroll
        for (int k = 1; k < 4; ++k) {
          const float nw = t4[13 + k], od = t4[2 + k];
          s += nw - od;
          ss = fmaf(nw, nw, fmaf(-od, od, ss));
          su[k] = s; suu[k] = ss;
        }
      }
      {  // field v
        float4 q;
        q = vs4[rb    ]; t4[0]=q.x;  t4[1]=q.y;  t4[2]=q.z;  t4[3]=q.w;
        q = vs4[rb + 1]; t4[4]=q.x;  t4[5]=q.y;  t4[6]=q.z;  t4[7]=q.w;
        q = vs4[rb + 2]; t4[8]=q.x;  t4[9]=q.y;  t4[10]=q.z; t4[11]=q.w;
        q = vs4[rb + 3]; t4[12]=q.x; t4[13]=q.y; t4[14]=q.z; t4[15]=q.w;
        q = vs4[rb + 4]; t4[16]=q.x; t4[17]=q.y; t4[18]=q.z; t4[19]=q.w;
        float s = 0.f, ss = 0.f;
#pragma unroll
        for (int j = 3; j <= 13; ++j) { s += t4[j]; ss = fmaf(t4[j], t4[j], ss); }
        sv[0] = s; svv[0] = ss;
#pragma unroll
        for (int k = 1; k < 4; ++k) {
          const float nw = t4[13 + k], od = t4[2 + k];
          s += nw - od;
          ss = fmaf(nw, nw, fmaf(-od, od, ss));
          sv[k] = s; svv[k] = ss;
        }
      }
#pragma unroll
      for (int k = 0; k < 4; ++k)
        wpf[o + k] = make_float4(su[k], sv[k], suu[k], svv[k]);
    }
    __syncthreads();

    // --- H-pass: 64 threads x 4 sliding outputs (14 b128 reads, 4 writes) ---
    if (dval && tid < 64) {
      const int qt = tid >> 4, hw = tid & 15;
      const int base = (qt << 2) * WPS + hw;
      const float4 T0 = wpf[base];
      const float4 T1 = wpf[base + WPS];
      const float4 T2 = wpf[base + 2 * WPS];
      float4 S = f4add(f4add(T0, T1), T2);
#pragma unroll
      for (int j = 3; j <= 10; ++j) S = f4add(S, wpf[base + j * WPS]);
      Sb[((qt << 2) + 0) * TS + hw] = S;
      S = f4sub(f4add(S, wpf[base + 11 * WPS]), T0);
      Sb[((qt << 2) + 1) * TS + hw] = S;
      S = f4sub(f4add(S, wpf[base + 12 * WPS]), T1);
      Sb[((qt << 2) + 2) * TS + hw] = S;
      S = f4sub(f4add(S, wpf[base + 13 * WPS]), T2);
      Sb[((qt << 2) + 3) * TS + hw] = S;
    }
    __syncthreads();

    // --- redistribute + D-ring update + SSIM ---
    float4 Sv = make_float4(0.f, 0.f, 0.f, 0.f);
    if (dval) Sv = Sb[tid];
    switch (ph) {
      RING_CASE(0) RING_CASE(1) RING_CASE(2) RING_CASE(3) RING_CASE(4)
      RING_CASE(5) RING_CASE(6) RING_CASE(7) RING_CASE(8) RING_CASE(9)
      RING_CASE(10)
    }
    ph = (ph == 10) ? 0 : ph + 1;
    if (d >= c0 + PAD) ssloc += ssim_term(sums, inv, c1, c2);
  }

  // --- block reduction -> per-block partials ---
#pragma unroll
  for (int off = 32; off > 0; off >>= 1) {
    ssloc += __shfl_down(ssloc, off, 64);
    l1loc += __shfl_down(l1loc, off, 64);
  }
  __syncthreads();                 // LDS compute use done; reuse Sb as scratch
  float* scr = (float*)Sb;
  const int lane = tid & 63, wv = tid >> 6;
  if (lane == 0) {
    scr[wv * 2]     = ssloc;
    scr[wv * 2 + 1] = l1loc;
  }
  __syncthreads();
  if (tid == 0) {
    pssim[bx] = scr[0] + scr[2] + scr[4] + scr[6];
    pl1[bx]   = scr[1] + scr[3] + scr[5] + scr[7];
  }
}

// Final: reduce 1600 + 1600 partials in double, emit scalar loss.
__global__ __launch_bounds__(256) void final_reduce(const float* __restrict__ pssim,
                                                    const float* __restrict__ pl1,
                                                    float* __restrict__ out) {
  double s = 0.0, l = 0.0;
  for (int i = threadIdx.x; i < NBLK; i += 256) {
    s += (double)pssim[i];
    l += (double)pl1[i];
  }
#pragma unroll
  for (int off = 32; off > 0; off >>= 1) {
    s += __shfl_down(s, off, 64);
    l += __shfl_down(l, off, 64);
  }
  __shared__ double sm[8];
  const int lane = threadIdx.x & 63, wv = threadIdx.x >> 6;
  if (lane == 0) { sm[wv * 2] = s; sm[wv * 2 + 1] = l; }
  __syncthreads();
  if (threadIdx.x == 0) {
    const double ssm = (sm[0] + sm[2] + sm[4] + sm[6]) / (double)NTOT;
    const double l1m = (sm[1] + sm[3] + sm[5] + sm[7]) / (double)NTOT;
    out[0] = (float)(0.85 * ssm + 0.15 * l1m);
  }
}

extern "C" void kernel_launch(void* const* d_in, const int* in_sizes, int n_in,
                              void* d_out, int out_size, void* d_ws, size_t ws_size,
                              hipStream_t stream) {
  const float* X = (const float*)d_in[0];
  const float* Y = (const float*)d_in[1];
  float* out = (float*)d_out;

  float* pssim = (float*)d_ws;        // NBLK floats
  float* pl1   = pssim + NBLK;        // NBLK floats

  fused_ssim<<<NBLK, 256, 0, stream>>>(X, Y, pssim, pl1);
  final_reduce<<<1, 256, 0, stream>>>(pssim, pl1, out);
}

// Round 10
// 170.707 us; speedup vs baseline: 1.2695x; 1.0001x over previous
//
#include <hip/hip_runtime.h>

// Shape fixed by reference: (2,1,160,160,160) fp32, window 11, zero-pad box filter.
// Fields reduced via u=x+y, v=x-y: box{u, v, u^2, v^2} packed in one float4.
// R9 = R4 structure (best measured) + 8-output sliding W-phase (52 thr = 1 wave,
//      20 wave-LDS-instr vs 28). No swizzle (R8: -76% FETCH but +3.5% dur).
#define DIMX 160
#define DIMY 160
#define DIMZ 160
#define BC   2
#define NTOT (BC * DIMZ * DIMY * DIMX)   // 8,192,000
#define PAD  5
#define TS   16                  // tile size in H and W
#define HS   26                  // TS + 2*PAD rows
#define XS4  10                  // stage row stride in float4 (8 used + 2 pad)
#define WPS  17                  // wp row stride in float4 (breaks bank aliasing)
#define CD   20                  // D-chunk per block
#define NCH  (DIMZ / CD)         // 8
#define NTH  (DIMY / TS)         // 10
#define NTW  (DIMX / TS)         // 10
#define NBLK (NCH * BC * NTH * NTW)  // 1600 blocks

static_assert(NTOT == 8192000, "size mismatch");

__device__ __forceinline__ float4 f4add(float4 a, float4 b) {
  return make_float4(a.x + b.x, a.y + b.y, a.z + b.z, a.w + b.w);
}
__device__ __forceinline__ float4 f4sub(float4 a, float4 b) {
  return make_float4(a.x - b.x, a.y - b.y, a.z - b.z, a.w - b.w);
}

// Ring slot update with compile-time index K (keeps ring[] in VGPRs).
#define RING_CASE(K) case K: {                 \
    sums = f4add(sums, f4sub(Sv, ring[K]));    \
    ring[K] = Sv;                              \
  } break;

__device__ __forceinline__ float ssim_term(float4 sm, float inv, float c1, float c2) {
  const float mu_u = sm.x * inv, mu_v = sm.y * inv;
  const float Euu  = sm.z * inv, Evv  = sm.w * inv;
  const float P = mu_u * mu_u, Q = mu_v * mu_v;
  const float sgu = Euu - P, sgv = Evv - Q;
  const float num = (0.5f * (P - Q) + c1) * (0.5f * (sgu - sgv) + c2);
  const float den = (0.5f * (P + Q) + c1) * (0.5f * (sgu + sgv) + c2);
  const float ssim = num * __builtin_amdgcn_rcpf(den + 1e-8f);
  const float val  = 0.5f * (1.f - ssim);
  return fminf(fmaxf(val, 0.f), 1.f);
}

__global__ __launch_bounds__(256) void fused_ssim(const float* __restrict__ X,
                                                  const float* __restrict__ Y,
                                                  float* __restrict__ pssim,
                                                  float* __restrict__ pl1) {
  __shared__ float4 us4[HS * XS4];   // staged u slab (26 rows x 8 used float4)
  __shared__ float4 vs4[HS * XS4];   // staged v slab
  __shared__ float4 wpf[HS * WPS];   // W-passed {su,sv,suu,svv}, stride 17
  __shared__ float4 Sb[TS * TS];     // H-passed per-voxel field vector

  const int tid = threadIdx.x;
  const int bx  = blockIdx.x;
  const int tw  = bx % NTW;
  const int th  = (bx / NTW) % NTH;
  const int b   = (bx / (NTW * NTH)) % BC;
  const int ch  =  bx / (NTW * NTH * BC);
  const int h0 = th * TS, w0 = tw * TS, c0 = ch * CD;
  const size_t bbase = (size_t)b * (DIMZ * DIMY * DIMX);

  // staging decomposition: 208 threads = 26 rows x 8 float4-cols (w0-8 .. w0+23)
  const int sr  = tid >> 3, sc4 = tid & 7;
  const int sgh = h0 - PAD + sr;
  const int sgw = w0 - 8 + (sc4 << 2);
  const bool sok = (tid < 208) && ((unsigned)sgh < (unsigned)DIMY) &&
                   ((unsigned)sgw < (unsigned)DIMX);
  const bool l1own = (sr >= PAD) && (sr < PAD + TS) && (sc4 >= 2) && (sc4 < 6);
  const size_t sgoff = bbase + (size_t)sgh * DIMX + sgw;   // only used when sok

  // W-pass decomposition (tid < 52, single wave): 26 rows x 2 groups of 8 outputs
  const int wr = tid >> 1, wg = tid & 1;

  float4 ring[11];
#pragma unroll
  for (int k = 0; k < 11; ++k) ring[k] = make_float4(0.f, 0.f, 0.f, 0.f);
  float4 sums = make_float4(0.f, 0.f, 0.f, 0.f);
  float l1loc = 0.f, ssloc = 0.f;

  const float inv = 1.0f / 1331.0f;             // 1/11^3
  const float c1  = 0.01f / (4096.f * 4096.f);  // K1 / data_range^2 (faithful to ref)
  const float c2  = 0.03f / (4096.f * 4096.f);

  // prefetch first slab (d = c0-PAD) into regs
  float4 xq = make_float4(0.f, 0.f, 0.f, 0.f), yq = xq;
  if (sok && (unsigned)(c0 - PAD) < (unsigned)DIMZ) {
    const size_t g = sgoff + (size_t)(c0 - PAD) * (DIMY * DIMX);
    xq = *(const float4*)(X + g);
    yq = *(const float4*)(Y + g);
  }

  int ph = (c0 - PAD + 22) % 11;   // uniform ring phase

  for (int d = c0 - PAD; d < c0 + CD + PAD; ++d) {
    const bool dval = (unsigned)d < (unsigned)DIMZ;
    const bool dIn  = (d >= c0) && (d < c0 + CD);

    // --- stage u,v from prefetched regs; fuse smooth-L1; issue next prefetch ---
    if (tid < 208) {
      if (dval) {
        const float4 u = f4add(xq, yq);
        const float4 v = f4sub(xq, yq);
        us4[sr * XS4 + sc4] = u;
        vs4[sr * XS4 + sc4] = v;
        if (dIn && l1own) {
          const float a0 = fabsf(v.x), a1 = fabsf(v.y);
          const float a2 = fabsf(v.z), a3 = fabsf(v.w);
          l1loc += (a0 < 1.f) ? 0.5f * a0 * a0 : a0 - 0.5f;
          l1loc += (a1 < 1.f) ? 0.5f * a1 * a1 : a1 - 0.5f;
          l1loc += (a2 < 1.f) ? 0.5f * a2 * a2 : a2 - 0.5f;
          l1loc += (a3 < 1.f) ? 0.5f * a3 * a3 : a3 - 0.5f;
        }
      }
      const int dn = d + 1;
      if (sok && (unsigned)dn < (unsigned)DIMZ) {
        const size_t g = sgoff + (size_t)dn * (DIMY * DIMX);
        xq = *(const float4*)(X + g);   // in flight across the barriers below
        yq = *(const float4*)(Y + g);
      } else {
        xq = make_float4(0.f, 0.f, 0.f, 0.f);
        yq = make_float4(0.f, 0.f, 0.f, 0.f);
      }
    }
    __syncthreads();

    // --- W-pass: 52 threads (1 wave) x 8 sliding outputs; 6 b128 reads/field ---
    if (dval && tid < 52) {
      const int rb = wr * XS4 + (wg << 1);
      const int o  = wr * WPS + (wg << 3);
      float tu[24], tv[24];
      float4 q;
      q = us4[rb    ]; tu[0]=q.x;  tu[1]=q.y;  tu[2]=q.z;  tu[3]=q.w;
      q = us4[rb + 1]; tu[4]=q.x;  tu[5]=q.y;  tu[6]=q.z;  tu[7]=q.w;
      q = us4[rb + 2]; tu[8]=q.x;  tu[9]=q.y;  tu[10]=q.z; tu[11]=q.w;
      q = us4[rb + 3]; tu[12]=q.x; tu[13]=q.y; tu[14]=q.z; tu[15]=q.w;
      q = us4[rb + 4]; tu[16]=q.x; tu[17]=q.y; tu[18]=q.z; tu[19]=q.w;
      q = us4[rb + 5]; tu[20]=q.x; tu[21]=q.y; tu[22]=q.z; tu[23]=q.w;
      q = vs4[rb    ]; tv[0]=q.x;  tv[1]=q.y;  tv[2]=q.z;  tv[3]=q.w;
      q = vs4[rb + 1]; tv[4]=q.x;  tv[5]=q.y;  tv[6]=q.z;  tv[7]=q.w;
      q = vs4[rb + 2]; tv[8]=q.x;  tv[9]=q.y;  tv[10]=q.z; tv[11]=q.w;
      q = vs4[rb + 3]; tv[12]=q.x; tv[13]=q.y; tv[14]=q.z; tv[15]=q.w;
      q = vs4[rb + 4]; tv[16]=q.x; tv[17]=q.y; tv[18]=q.z; tv[19]=q.w;
      q = vs4[rb + 5]; tv[20]=q.x; tv[21]=q.y; tv[22]=q.z; tv[23]=q.w;

      float su = 0.f, ssu = 0.f, sv = 0.f, ssv = 0.f;
#pragma unroll
      for (int j = 3; j <= 13; ++j) {
        su += tu[j]; ssu = fmaf(tu[j], tu[j], ssu);
        sv += tv[j]; ssv = fmaf(tv[j], tv[j], ssv);
      }
      wpf[o] = make_float4(su, sv, ssu, ssv);
#pragma unroll
      for (int k = 1; k < 8; ++k) {
        const float nu = tu[13 + k], ou = tu[2 + k];
        const float nv = tv[13 + k], ov = tv[2 + k];
        su += nu - ou; ssu = fmaf(nu, nu, fmaf(-ou, ou, ssu));
        sv += nv - ov; ssv = fmaf(nv, nv, fmaf(-ov, ov, ssv));
        wpf[o + k] = make_float4(su, sv, ssu, ssv);
      }
    }
    __syncthreads();

    // --- H-pass: 64 threads (1 wave) x 4 sliding outputs (14 reads, 4 writes) ---
    if (dval && tid < 64) {
      const int qt = tid >> 4, hw = tid & 15;
      const int base = (qt << 2) * WPS + hw;
      const float4 T0 = wpf[base];
      const float4 T1 = wpf[base + WPS];
      const float4 T2 = wpf[base + 2 * WPS];
      float4 S = f4add(f4add(T0, T1), T2);
#pragma unroll
      for (int j = 3; j <= 10; ++j) S = f4add(S, wpf[base + j * WPS]);
      Sb[((qt << 2) + 0) * TS + hw] = S;
      S = f4sub(f4add(S, wpf[base + 11 * WPS]), T0);
      Sb[((qt << 2) + 1) * TS + hw] = S;
      S = f4sub(f4add(S, wpf[base + 12 * WPS]), T1);
      Sb[((qt << 2) + 2) * TS + hw] = S;
      S = f4sub(f4add(S, wpf[base + 13 * WPS]), T2);
      Sb[((qt << 2) + 3) * TS + hw] = S;
    }
    __syncthreads();

    // --- redistribute + D-ring update + SSIM ---
    float4 Sv = make_float4(0.f, 0.f, 0.f, 0.f);
    if (dval) Sv = Sb[tid];
    switch (ph) {
      RING_CASE(0) RING_CASE(1) RING_CASE(2) RING_CASE(3) RING_CASE(4)
      RING_CASE(5) RING_CASE(6) RING_CASE(7) RING_CASE(8) RING_CASE(9)
      RING_CASE(10)
    }
    ph = (ph == 10) ? 0 : ph + 1;
    if (d >= c0 + PAD) ssloc += ssim_term(sums, inv, c1, c2);
  }

  // --- block reduction -> per-block partials ---
#pragma unroll
  for (int off = 32; off > 0; off >>= 1) {
    ssloc += __shfl_down(ssloc, off, 64);
    l1loc += __shfl_down(l1loc, off, 64);
  }
  __syncthreads();                 // LDS compute use done; reuse Sb as scratch
  float* scr = (float*)Sb;
  const int lane = tid & 63, wv = tid >> 6;
  if (lane == 0) {
    scr[wv * 2]     = ssloc;
    scr[wv * 2 + 1] = l1loc;
  }
  __syncthreads();
  if (tid == 0) {
    pssim[bx] = scr[0] + scr[2] + scr[4] + scr[6];
    pl1[bx]   = scr[1] + scr[3] + scr[5] + scr[7];
  }
}

// Final: reduce 1600 + 1600 partials in double, emit scalar loss.
__global__ __launch_bounds__(256) void final_reduce(const float* __restrict__ pssim,
                                                    const float* __restrict__ pl1,
                                                    float* __restrict__ out) {
  double s = 0.0, l = 0.0;
  for (int i = threadIdx.x; i < NBLK; i += 256) {
    s += (double)pssim[i];
    l += (double)pl1[i];
  }
#pragma unroll
  for (int off = 32; off > 0; off >>= 1) {
    s += __shfl_down(s, off, 64);
    l += __shfl_down(l, off, 64);
  }
  __shared__ double sm[8];
  const int lane = threadIdx.x & 63, wv = threadIdx.x >> 6;
  if (lane == 0) { sm[wv * 2] = s; sm[wv * 2 + 1] = l; }
  __syncthreads();
  if (threadIdx.x == 0) {
    const double ssm = (sm[0] + sm[2] + sm[4] + sm[6]) / (double)NTOT;
    const double l1m = (sm[1] + sm[3] + sm[5] + sm[7]) / (double)NTOT;
    out[0] = (float)(0.85 * ssm + 0.15 * l1m);
  }
}

extern "C" void kernel_launch(void* const* d_in, const int* in_sizes, int n_in,
                              void* d_out, int out_size, void* d_ws, size_t ws_size,
                              hipStream_t stream) {
  const float* X = (const float*)d_in[0];
  const float* Y = (const float*)d_in[1];
  float* out = (float*)d_out;

  float* pssim = (float*)d_ws;        // NBLK floats
  float* pl1   = pssim + NBLK;        // NBLK floats

  fused_ssim<<<NBLK, 256, 0, stream>>>(X, Y, pssim, pl1);
  final_reduce<<<1, 256, 0, stream>>>(pssim, pl1, out);
}